// Round 4
// baseline (29.676 us; speedup 1.0000x reference)
//
#include <hip/hip_runtime.h>

#define THRESH_SQ 0.1f
#define TINY 1e-6f

typedef float vf2 __attribute__((ext_vector_type(2)));
typedef float vf4 __attribute__((ext_vector_type(4)));

__global__ void __launch_bounds__(256) se3_kernel(const float* __restrict__ in,
                                                  float* __restrict__ out, int n) {
    __shared__ vf2 lin[768];    // 6 KB input staging
    __shared__ vf4 lout[768];   // 12 KB output staging
    int tid = threadIdx.x;
    long long base = (long long)blockIdx.x * 256;
    int rem = n - (int)base;       // rows handled by this block (<=256)

    // ---- coalesced, non-temporal input load: block's 6 KB region ----
    const vf2* in2 = reinterpret_cast<const vf2*>(in) + base * 3;
    if (rem >= 256) {
        lin[tid]       = __builtin_nontemporal_load(&in2[tid]);
        lin[tid + 256] = __builtin_nontemporal_load(&in2[tid + 256]);
        lin[tid + 512] = __builtin_nontemporal_load(&in2[tid + 512]);
    } else if (rem > 0) {
        int nf2 = rem * 3;
        for (int j = tid; j < nf2; j += 256)
            lin[j] = __builtin_nontemporal_load(&in2[j]);
    }
    __syncthreads();

    if (tid < rem) {
        // row layout: [rho0, rho1, rho2, w0, w1, w2]; oz=w0, oy=w1, ox=w2
        vf2 v0 = lin[tid * 3];
        vf2 v1 = lin[tid * 3 + 1];
        vf2 v2 = lin[tid * 3 + 2];
        float r0 = v0.x, r1 = v0.y, r2 = v1.x;
        float oz = v1.y, oy = v2.x, ox = v2.y;

        float aa = ox * ox, bb = oy * oy, cc = oz * oz;
        float t2 = aa + bb + cc;
        float theta = sqrtf(t2);
        float s = __sinf(theta);
        float c = __cosf(theta);

        float sdt = (theta > 0.f) ? (s / theta) : 0.f;

        float t4 = t2 * t2;
        float t6 = t4 * t2;
        float t8 = t4 * t4;
        float t3 = t2 * theta;

        // A = (1-cos)/t2 for t2>0.1, 0 for t2<1e-6, Taylor otherwise
        float A_taylor = 0.5f + t4 / 720.f + t8 / 3628800.f - t2 / 24.f - t6 / 40320.f;
        float A = (t2 > THRESH_SQ) ? ((1.f - c) / t2)
                                   : ((t2 < TINY) ? 0.f : A_taylor);

        // B = (theta-sin)/t3 for t3>0.1, 0 for t2<1e-6, Taylor otherwise
        float B_taylor = 1.f / 6.f + t4 / 5040.f + t8 / 39916800.f - t2 / 120.f - t6 / 362880.f;
        float B = (t3 > 0.1f) ? ((theta - s) / t3)
                              : ((t2 < TINY) ? 0.f : B_taylor);

        float ab = ox * oy, ac = ox * oz, bc = oy * oz;

        float R00 = 1.f - A * (cc + bb);
        float R01 = -sdt * oz + A * ab;
        float R02 =  sdt * oy + A * ac;
        float R10 =  sdt * oz + A * ab;
        float R11 = 1.f - A * (cc + aa);
        float R12 = -sdt * ox + A * bc;
        float R20 = -sdt * oy + A * ac;
        float R21 =  sdt * ox + A * bc;
        float R22 = 1.f - A * (aa + bb);

        float V00 = 1.f - B * (cc + bb);
        float V01 = -A * oz + B * ab;
        float V02 =  A * oy + B * ac;
        float V10 =  A * oz + B * ab;
        float V11 = 1.f - B * (cc + aa);
        float V12 = -A * ox + B * bc;
        float V20 = -A * oy + B * ac;
        float V21 =  A * ox + B * bc;
        float V22 = 1.f - B * (aa + bb);

        float tr0 = V00 * r0 + V01 * r1 + V02 * r2;
        float tr1 = V10 * r0 + V11 * r1 + V12 * r2;
        float tr2 = V20 * r0 + V21 * r1 + V22 * r2;

        lout[tid * 3]     = (vf4){R00, R01, R02, tr0};
        lout[tid * 3 + 1] = (vf4){R10, R11, R12, tr1};
        lout[tid * 3 + 2] = (vf4){R20, R21, R22, tr2};
    }
    __syncthreads();

    // ---- coalesced, non-temporal block write: 768 contiguous float4 ----
    vf4* ob = reinterpret_cast<vf4*>(out) + base * 3;
    if (rem >= 256) {
        __builtin_nontemporal_store(lout[tid],       &ob[tid]);
        __builtin_nontemporal_store(lout[tid + 256], &ob[tid + 256]);
        __builtin_nontemporal_store(lout[tid + 512], &ob[tid + 512]);
    } else if (rem > 0) {
        int nf4 = rem * 3;
        for (int j = tid; j < nf4; j += 256)
            __builtin_nontemporal_store(lout[j], &ob[j]);
    }
}

extern "C" void kernel_launch(void* const* d_in, const int* in_sizes, int n_in,
                              void* d_out, int out_size, void* d_ws, size_t ws_size,
                              hipStream_t stream) {
    const float* vec = (const float*)d_in[0];
    float* out = (float*)d_out;
    int n = in_sizes[0] / 6;
    int blocks = (n + 255) / 256;
    se3_kernel<<<blocks, 256, 0, stream>>>(vec, out, n);
}

// Round 5
// 27.657 us; speedup vs baseline: 1.0730x; 1.0730x over previous
//
#include <hip/hip_runtime.h>

#define THRESH_SQ 0.1f
#define TINY 1e-6f

typedef float vf2 __attribute__((ext_vector_type(2)));
typedef float vf4 __attribute__((ext_vector_type(4)));

__global__ void __launch_bounds__(256) se3_kernel(const float* __restrict__ in,
                                                  float* __restrict__ out, int n) {
    __shared__ vf4 lout[768];   // 12 KB output staging
    int tid = threadIdx.x;
    long long base = (long long)blockIdx.x * 256;
    int i = (int)base + tid;

    if (i < n) {
        // row layout: [rho0, rho1, rho2, w0, w1, w2]; oz=w0, oy=w1, ox=w2
        const vf2* p = reinterpret_cast<const vf2*>(in) + (size_t)i * 3;
        vf2 v0 = p[0];
        vf2 v1 = p[1];
        vf2 v2 = p[2];
        float r0 = v0.x, r1 = v0.y, r2 = v1.x;
        float oz = v1.y, oy = v2.x, ox = v2.y;

        float aa = ox * ox, bb = oy * oy, cc = oz * oz;
        float t2 = aa + bb + cc;
        float theta = sqrtf(t2);
        float s = __sinf(theta);
        float c = __cosf(theta);

        float sdt = (theta > 0.f) ? (s / theta) : 0.f;

        float t4 = t2 * t2;
        float t6 = t4 * t2;
        float t8 = t4 * t4;
        float t3 = t2 * theta;

        // A = (1-cos)/t2 for t2>0.1, 0 for t2<1e-6, Taylor otherwise
        float A_taylor = 0.5f + t4 / 720.f + t8 / 3628800.f - t2 / 24.f - t6 / 40320.f;
        float A = (t2 > THRESH_SQ) ? ((1.f - c) / t2)
                                   : ((t2 < TINY) ? 0.f : A_taylor);

        // B = (theta-sin)/t3 for t3>0.1, 0 for t2<1e-6, Taylor otherwise
        float B_taylor = 1.f / 6.f + t4 / 5040.f + t8 / 39916800.f - t2 / 120.f - t6 / 362880.f;
        float B = (t3 > 0.1f) ? ((theta - s) / t3)
                              : ((t2 < TINY) ? 0.f : B_taylor);

        float ab = ox * oy, ac = ox * oz, bc = oy * oz;

        float R00 = 1.f - A * (cc + bb);
        float R01 = -sdt * oz + A * ab;
        float R02 =  sdt * oy + A * ac;
        float R10 =  sdt * oz + A * ab;
        float R11 = 1.f - A * (cc + aa);
        float R12 = -sdt * ox + A * bc;
        float R20 = -sdt * oy + A * ac;
        float R21 =  sdt * ox + A * bc;
        float R22 = 1.f - A * (aa + bb);

        float V00 = 1.f - B * (cc + bb);
        float V01 = -A * oz + B * ab;
        float V02 =  A * oy + B * ac;
        float V10 =  A * oz + B * ab;
        float V11 = 1.f - B * (cc + aa);
        float V12 = -A * ox + B * bc;
        float V20 = -A * oy + B * ac;
        float V21 =  A * ox + B * bc;
        float V22 = 1.f - B * (aa + bb);

        float tr0 = V00 * r0 + V01 * r1 + V02 * r2;
        float tr1 = V10 * r0 + V11 * r1 + V12 * r2;
        float tr2 = V20 * r0 + V21 * r1 + V22 * r2;

        lout[tid * 3]     = (vf4){R00, R01, R02, tr0};
        lout[tid * 3 + 1] = (vf4){R10, R11, R12, tr1};
        lout[tid * 3 + 2] = (vf4){R20, R21, R22, tr2};
    }
    __syncthreads();

    // ---- coalesced, non-temporal block write: 768 contiguous float4 ----
    int rem = n - (int)base;
    vf4* ob = reinterpret_cast<vf4*>(out) + base * 3;
    if (rem >= 256) {
        __builtin_nontemporal_store(lout[tid],       &ob[tid]);
        __builtin_nontemporal_store(lout[tid + 256], &ob[tid + 256]);
        __builtin_nontemporal_store(lout[tid + 512], &ob[tid + 512]);
    } else if (rem > 0) {
        int nf4 = rem * 3;
        for (int j = tid; j < nf4; j += 256)
            __builtin_nontemporal_store(lout[j], &ob[j]);
    }
}

extern "C" void kernel_launch(void* const* d_in, const int* in_sizes, int n_in,
                              void* d_out, int out_size, void* d_ws, size_t ws_size,
                              hipStream_t stream) {
    const float* vec = (const float*)d_in[0];
    float* out = (float*)d_out;
    int n = in_sizes[0] / 6;
    int blocks = (n + 255) / 256;
    se3_kernel<<<blocks, 256, 0, stream>>>(vec, out, n);
}

// Round 6
// 27.633 us; speedup vs baseline: 1.0739x; 1.0009x over previous
//
#include <hip/hip_runtime.h>

#define THRESH_SQ 0.1f
#define TINY 1e-6f

typedef float vf4 __attribute__((ext_vector_type(4)));

__device__ __forceinline__ void se3_row(float r0, float r1, float r2,
                                        float oz, float oy, float ox,
                                        vf4& o0, vf4& o1, vf4& o2) {
    float aa = ox * ox, bb = oy * oy, cc = oz * oz;
    float t2 = aa + bb + cc;
    float theta = sqrtf(t2);
    float s = __sinf(theta);
    float c = __cosf(theta);

    float sdt = (theta > 0.f) ? (s / theta) : 0.f;

    float t4 = t2 * t2;
    float t6 = t4 * t2;
    float t8 = t4 * t4;
    float t3 = t2 * theta;

    float A_taylor = 0.5f + t4 / 720.f + t8 / 3628800.f - t2 / 24.f - t6 / 40320.f;
    float A = (t2 > THRESH_SQ) ? ((1.f - c) / t2)
                               : ((t2 < TINY) ? 0.f : A_taylor);

    float B_taylor = 1.f / 6.f + t4 / 5040.f + t8 / 39916800.f - t2 / 120.f - t6 / 362880.f;
    float B = (t3 > 0.1f) ? ((theta - s) / t3)
                          : ((t2 < TINY) ? 0.f : B_taylor);

    float ab = ox * oy, ac = ox * oz, bc = oy * oz;

    float R00 = 1.f - A * (cc + bb);
    float R01 = -sdt * oz + A * ab;
    float R02 =  sdt * oy + A * ac;
    float R10 =  sdt * oz + A * ab;
    float R11 = 1.f - A * (cc + aa);
    float R12 = -sdt * ox + A * bc;
    float R20 = -sdt * oy + A * ac;
    float R21 =  sdt * ox + A * bc;
    float R22 = 1.f - A * (aa + bb);

    float V00 = 1.f - B * (cc + bb);
    float V01 = -A * oz + B * ab;
    float V02 =  A * oy + B * ac;
    float V10 =  A * oz + B * ab;
    float V11 = 1.f - B * (cc + aa);
    float V12 = -A * ox + B * bc;
    float V20 = -A * oy + B * ac;
    float V21 =  A * ox + B * bc;
    float V22 = 1.f - B * (aa + bb);

    float tr0 = V00 * r0 + V01 * r1 + V02 * r2;
    float tr1 = V10 * r0 + V11 * r1 + V12 * r2;
    float tr2 = V20 * r0 + V21 * r1 + V22 * r2;

    o0 = (vf4){R00, R01, R02, tr0};
    o1 = (vf4){R10, R11, R12, tr1};
    o2 = (vf4){R20, R21, R22, tr2};
}

__global__ void __launch_bounds__(256) se3_kernel(const float* __restrict__ in,
                                                  float* __restrict__ out, int n) {
    __shared__ vf4 lout[1536];   // 24 KB output staging (512 rows * 3 vf4)
    int tid = threadIdx.x;
    long long base = (long long)blockIdx.x * 512;
    int i0 = (int)base + 2 * tid;     // first row of this thread's pair
    int i1 = i0 + 1;

    // per-thread 48 B contiguous input: 3 x vf4 covering rows i0, i1
    const vf4* p = reinterpret_cast<const vf4*>(in + base * 6) + 3 * tid;
    vf4 q0, q1, q2;
    if (i1 < n) {
        q0 = p[0]; q1 = p[1]; q2 = p[2];
    } else if (i0 < n) {
        q0 = p[0]; q1 = p[1]; q2 = (vf4){0.f, 0.f, 0.f, 0.f};
    }

    if (i0 < n) {
        vf4 o0, o1, o2;
        // row layout: [rho0,rho1,rho2,w0,w1,w2]; oz=w0, oy=w1, ox=w2
        se3_row(q0.x, q0.y, q0.z, q0.w, q1.x, q1.y, o0, o1, o2);
        lout[6 * tid]     = o0;
        lout[6 * tid + 1] = o1;
        lout[6 * tid + 2] = o2;
    }
    if (i1 < n) {
        vf4 o0, o1, o2;
        se3_row(q1.z, q1.w, q2.x, q2.y, q2.z, q2.w, o0, o1, o2);
        lout[6 * tid + 3] = o0;
        lout[6 * tid + 4] = o1;
        lout[6 * tid + 5] = o2;
    }
    __syncthreads();

    // coalesced non-temporal block write: 1536 contiguous vf4 (24 KB)
    int rem = n - (int)base;          // rows in this block (<=512)
    vf4* ob = reinterpret_cast<vf4*>(out) + base * 3;
    if (rem >= 512) {
        #pragma unroll
        for (int k = 0; k < 6; ++k)
            __builtin_nontemporal_store(lout[tid + k * 256], &ob[tid + k * 256]);
    } else if (rem > 0) {
        int nf4 = rem * 3;
        for (int j = tid; j < nf4; j += 256)
            __builtin_nontemporal_store(lout[j], &ob[j]);
    }
}

extern "C" void kernel_launch(void* const* d_in, const int* in_sizes, int n_in,
                              void* d_out, int out_size, void* d_ws, size_t ws_size,
                              hipStream_t stream) {
    const float* vec = (const float*)d_in[0];
    float* out = (float*)d_out;
    int n = in_sizes[0] / 6;
    int blocks = (n + 511) / 512;
    se3_kernel<<<blocks, 256, 0, stream>>>(vec, out, n);
}